// Round 2
// baseline (3258.686 us; speedup 1.0000x reference)
//
#include <hip/hip_runtime.h>

typedef unsigned int  u32;
typedef unsigned short u16;
typedef _Float16 half8 __attribute__((ext_vector_type(8)));
typedef short   short8 __attribute__((ext_vector_type(8)));
typedef float   f32x4  __attribute__((ext_vector_type(4)));

#define T_LEN 512
#define BATCH 64
#define EDIM  256
#define HDIM  256
#define G4    1024   // 4*H gate rows

// ---------- numeric helpers ----------
static __device__ __forceinline__ u16 f2bf(float f) {
  u32 u = __builtin_bit_cast(u32, f);
  u = (u + 0x7fffu + ((u >> 16) & 1u)) >> 16;   // RTNE
  return (u16)u;
}
static __device__ __forceinline__ u16 f2h(float a) {
  _Float16 ha = (_Float16)a;
  return __builtin_bit_cast(u16, ha);
}
static __device__ __forceinline__ float h2f(u16 a) {
  return (float)__builtin_bit_cast(_Float16, a);
}
static __device__ __forceinline__ float sigf(float x) {
  return 1.0f / (1.0f + __expf(-x));
}
static __device__ __forceinline__ float tanhfast(float x) {
  return 2.0f / (1.0f + __expf(-2.0f * x)) - 1.0f;
}

// ---------- kernel 1: pack W_hh_f (f32 [1024x256]) into f16 MFMA A-frag order --
// Wf[mt][kt][lane][j] f16, flat ((mt*8+kt)*64+lane)*8+j.
// Value = W[mt*16 + (lane&15)][kt*32 + (lane>>4)*8 + j].
__global__ __launch_bounds__(256) void k_prep(const float* __restrict__ whh,
                                              u16* __restrict__ Wf) {
  int cell = blockIdx.x * 256 + threadIdx.x;  // 32768 cells, 8 f16 each
  int mt = cell >> 9, kt = (cell >> 6) & 7, l = cell & 63;
  int gr = mt * 16 + (l & 15);
  int c0 = kt * 32 + (l >> 4) * 8;
  const float4* src = (const float4*)(whh + (size_t)gr * 256 + c0);
  float4 a = src[0], b = src[1];
  u16 o[8] = { f2h(a.x), f2h(a.y), f2h(a.z), f2h(a.w),
               f2h(b.x), f2h(b.y), f2h(b.z), f2h(b.w) };
  uint4* dst = (uint4*)(Wf + (size_t)cell * 8);
  *dst = *(uint4*)o;
}

// ---------- kernel 2: xproj via bf16 MFMA, output f16 in k_rnn D-frag order ---
// xp2[t][bg][mt][lane][r], flat ((((t*4+bg)*64+mt)*64+lane)*4+r), f16.
#define LDSPITCH 264
__global__ __launch_bounds__(256) void k_xproj(const int* __restrict__ x,
                                               const float* __restrict__ emb,
                                               const float* __restrict__ wih,
                                               const float* __restrict__ bih,
                                               const float* __restrict__ bhh,
                                               u16* __restrict__ xp2) {
  __shared__ u16 smA[64 * LDSPITCH];
  __shared__ u16 smB[64 * LDSPITCH];
  const int tn = blockIdx.x, t = blockIdx.y;
  const int tid = threadIdx.x;
  const int r = tid >> 2, q4 = tid & 3;

  { // stage A: emb rows (batch r, timestep t), fp32 -> bf16
    int eidx = x[r * T_LEN + t];
    const float4* src = (const float4*)(emb + (size_t)eidx * EDIM + q4 * 64);
    u16* dst = smA + r * LDSPITCH + q4 * 64;
    #pragma unroll
    for (int i = 0; i < 16; ++i) {
      float4 v = src[i];
      uint2 p;
      p.x = (u32)f2bf(v.x) | ((u32)f2bf(v.y) << 16);
      p.y = (u32)f2bf(v.z) | ((u32)f2bf(v.w) << 16);
      *(uint2*)&dst[i * 4] = p;
    }
  }
  { // stage B: w_ih rows g = tn*64 + r
    const float4* src = (const float4*)(wih + (size_t)(tn * 64 + r) * EDIM + q4 * 64);
    u16* dst = smB + r * LDSPITCH + q4 * 64;
    #pragma unroll
    for (int i = 0; i < 16; ++i) {
      float4 v = src[i];
      uint2 p;
      p.x = (u32)f2bf(v.x) | ((u32)f2bf(v.y) << 16);
      p.y = (u32)f2bf(v.z) | ((u32)f2bf(v.w) << 16);
      *(uint2*)&dst[i * 4] = p;
    }
  }
  __syncthreads();

  const int wv = tid >> 6, lane = tid & 63;
  const int lm = lane & 15, q = lane >> 4;
  f32x4 acc[4];
  #pragma unroll
  for (int nt = 0; nt < 4; ++nt) acc[nt] = (f32x4){0.f, 0.f, 0.f, 0.f};

  const u16* pa = smA + (wv * 16 + lm) * LDSPITCH + q * 8;
  const u16* pb = smB + lm * LDSPITCH + q * 8;
  #pragma unroll
  for (int ks = 0; ks < 8; ++ks) {
    short8 av = *(const short8*)(pa + ks * 32);
    #pragma unroll
    for (int nt = 0; nt < 4; ++nt) {
      short8 bv = *(const short8*)(pb + nt * 16 * LDSPITCH + ks * 32);
      acc[nt] = __builtin_amdgcn_mfma_f32_16x16x32_bf16(av, bv, acc[nt], 0, 0, 0);
    }
  }
  // D: row = batch = wv*16 + q*4 + rr, col = gate = tn*64 + nt*16 + lm.
  // Target frag coords: mt = g>>4, qd = (g&15)>>2, rbit = g&3, lane' = qd*16+bl.
  #pragma unroll
  for (int nt = 0; nt < 4; ++nt) {
    int g = tn * 64 + nt * 16 + lm;
    float bias = bih[g] + bhh[g];
    int mt = g >> 4, qd = (g & 15) >> 2, rb = g & 3;
    #pragma unroll
    for (int rr = 0; rr < 4; ++rr) {
      int bl = q * 4 + rr;   // batch-in-group; bg = wv
      size_t idx = ((((size_t)t * 4 + wv) * 64 + mt) * 64 + (qd * 16 + bl)) * 4 + rb;
      xp2[idx] = f2h(acc[nt][rr] + bias);
    }
  }
}

// ---------- kernel 3: recurrence, 4 WGs x 512 thr, weights VGPR/LDS-resident --
// Wave w owns m-tiles {g*16 + 2w + p}. kt0-4 in VGPR, kt5-6 in LDS, kt7 streamed.
// LDS: A-frags 131072 B + hT dbuf 2*16*264*2 = 16896 B -> 147968 B dynamic.
__global__ __launch_bounds__(512, 2) void k_rnn(const u16* __restrict__ Wf,
                                                const u16* __restrict__ xp2,
                                                float* __restrict__ hf) {
  extern __shared__ u16 sm[];
  u16* smA = sm;             // 65536 u16
  u16* hT  = sm + 65536;     // 2 x 4224 u16
  const int bg = blockIdx.x;
  const int tid = threadIdx.x, w = tid >> 6, l = tid & 63;
  const int bl = l & 15, qd = l >> 4;

  { // zero hT (both buffers)
    u32* hz = (u32*)hT;
    #pragma unroll
    for (int k = 0; k < 9; ++k) { int i = tid + k * 512; if (i < 4224) hz[i] = 0; }
  }
  int mts[8];
  #pragma unroll
  for (int i = 0; i < 8; ++i) mts[i] = (i >> 1) * 16 + w * 2 + (i & 1);

  // resident A-frags kt0..4
  half8 wA[8][5];
  #pragma unroll
  for (int i = 0; i < 8; ++i)
    #pragma unroll
    for (int kt = 0; kt < 5; ++kt)
      wA[i][kt] = *(const half8*)(Wf + ((size_t)(mts[i] * 8 + kt) * 64 + l) * 8);
  // stage kt5,6 -> LDS
  #pragma unroll
  for (int i = 0; i < 8; ++i)
    #pragma unroll
    for (int s = 0; s < 2; ++s) {
      uint4 v = *(const uint4*)(Wf + ((size_t)(mts[i] * 8 + 5 + s) * 64 + l) * 8);
      *(uint4*)(smA + ((size_t)(w * 16 + i * 2 + s) * 64 + l) * 8) = v;
    }
  __syncthreads();

  float c[8];
  #pragma unroll
  for (int i = 0; i < 8; ++i) c[i] = 0.f;

  const u16* xptr = xp2 + (size_t)bg * 16384 + (size_t)l * 4;  // + t*65536 + mt*256
  const u16* wf7l = Wf + ((size_t)7 * 64 + l) * 8;             // + mt*4096

  f32x4 acc[8];
  for (int t = 0; t < T_LEN; ++t) {
    const u16* hb = hT + (t & 1) * 4224;
    u16*       hw = hT + ((t & 1) ^ 1) * 4224;
    #pragma unroll
    for (int i = 0; i < 8; ++i) acc[i] = (f32x4){0.f, 0.f, 0.f, 0.f};

    uint2 xv[8];
    uint4 As[8];
    #pragma unroll
    for (int kt = 0; kt < 8; ++kt) {
      if (kt == 1) {  // issue xproj loads (L3-resident, consumed at kt==4)
        #pragma unroll
        for (int i = 0; i < 8; ++i)
          xv[i] = *(const uint2*)(xptr + (size_t)mts[i] * 256);
      }
      if (kt == 5) {  // issue streamed kt7 A-frags, first half
        #pragma unroll
        for (int i = 0; i < 4; ++i)
          As[i] = *(const uint4*)(wf7l + (size_t)mts[i] * 4096);
      }
      if (kt == 6) {  // second half
        #pragma unroll
        for (int i = 4; i < 8; ++i)
          As[i] = *(const uint4*)(wf7l + (size_t)mts[i] * 4096);
      }
      half8 Bf = *(const half8*)(hb + bl * 264 + kt * 32 + qd * 8);
      #pragma unroll
      for (int i = 0; i < 8; ++i) {
        half8 Af;
        if (kt < 5)      Af = wA[i][kt];
        else if (kt < 7) Af = *(const half8*)(smA + ((size_t)(w * 16 + i * 2 + (kt - 5)) * 64 + l) * 8);
        else             Af = __builtin_bit_cast(half8, As[i]);
        acc[i] = __builtin_amdgcn_mfma_f32_16x16x32_f16(Af, Bf, acc[i], 0, 0, 0);
      }
      if (kt == 4) {  // fold in xproj term; frees xv before As goes live
        #pragma unroll
        for (int i = 0; i < 8; ++i) {
          acc[i][0] += h2f((u16)(xv[i].x & 0xffff));
          acc[i][1] += h2f((u16)(xv[i].x >> 16));
          acc[i][2] += h2f((u16)(xv[i].y & 0xffff));
          acc[i][3] += h2f((u16)(xv[i].y >> 16));
        }
      }
    }
    // h-update: lane has z_i/f/g/o for rows (2w+p)*16 + qd*4 + r, batch bl
    #pragma unroll
    for (int p = 0; p < 2; ++p)
      #pragma unroll
      for (int r = 0; r < 4; ++r) {
        float zi = acc[0 + p][r], zf = acc[2 + p][r];
        float zg = acc[4 + p][r], zo = acc[6 + p][r];
        int ci = p * 4 + r;
        c[ci] = sigf(zf) * c[ci] + sigf(zi) * tanhfast(zg);
        float hn = sigf(zo) * tanhfast(c[ci]);
        int row = (w * 2 + p) * 16 + qd * 4 + r;
        hw[bl * 264 + row] = f2h(hn);
        if (t == T_LEN - 1) hf[(bg * 16 + bl) * 256 + row] = hn;
      }
    __syncthreads();
    xptr += 65536;
  }
}

// ---------- kernel 4: backward single step + fc1 + fc2 ----------
__global__ __launch_bounds__(256) void k_tail(const int* __restrict__ x,
                                              const float* __restrict__ emb,
                                              const float* __restrict__ wihb,
                                              const float* __restrict__ bihb,
                                              const float* __restrict__ bhhb,
                                              const float* __restrict__ fc1w,
                                              const float* __restrict__ fc1b,
                                              const float* __restrict__ fc2w,
                                              const float* __restrict__ fc2b,
                                              const float* __restrict__ hf,
                                              float* __restrict__ out) {
  const int b = blockIdx.x, tid = threadIdx.x;
  __shared__ float e[EDIM], hb[HDIM], hfl[HDIM], f1[24];
  e[tid]   = emb[(size_t)x[b * T_LEN + (T_LEN - 1)] * EDIM + tid];
  hfl[tid] = hf[b * HDIM + tid];
  __syncthreads();

  float z[4];
  #pragma unroll
  for (int gq = 0; gq < 4; ++gq) {
    int g = gq * HDIM + tid;
    float s = bihb[g] + bhhb[g];
    const float4* wr = (const float4*)(wihb + (size_t)g * EDIM);
    #pragma unroll 8
    for (int k = 0; k < 64; ++k) {
      float4 w = wr[k];
      s += w.x * e[4 * k] + w.y * e[4 * k + 1] + w.z * e[4 * k + 2] + w.w * e[4 * k + 3];
    }
    z[gq] = s;
  }
  float cb = sigf(z[0]) * tanhfast(z[2]);   // c0 = 0
  hb[tid] = sigf(z[3]) * tanhfast(cb);
  __syncthreads();

  if (tid < 24) {
    float s = fc1b[tid];
    const float* w = fc1w + tid * 512;
    #pragma unroll 8
    for (int k = 0; k < HDIM; ++k) s += w[k] * hfl[k] + w[HDIM + k] * hb[k];
    f1[tid] = fmaxf(s, 0.f);
  }
  __syncthreads();
  if (tid < 2) {
    float s = fc2b[tid];
    #pragma unroll
    for (int k = 0; k < 24; ++k) s += fc2w[tid * 24 + k] * f1[k];
    out[b * 2 + tid] = s;
  }
}

// ---------- launch ----------
extern "C" void kernel_launch(void* const* d_in, const int* in_sizes, int n_in,
                              void* d_out, int out_size, void* d_ws, size_t ws_size,
                              hipStream_t stream) {
  const int*   x     = (const int*)  d_in[0];
  const float* emb   = (const float*)d_in[1];
  const float* wih_f = (const float*)d_in[2];
  const float* whh_f = (const float*)d_in[3];
  const float* bih_f = (const float*)d_in[4];
  const float* bhh_f = (const float*)d_in[5];
  const float* wih_b = (const float*)d_in[6];
  // d_in[7] = w_hh_b: unused (backward runs exactly one step from zero state)
  const float* bih_b = (const float*)d_in[8];
  const float* bhh_b = (const float*)d_in[9];
  const float* fc1w  = (const float*)d_in[10];
  const float* fc1b  = (const float*)d_in[11];
  const float* fc2w  = (const float*)d_in[12];
  const float* fc2b  = (const float*)d_in[13];
  float* out = (float*)d_out;

  // workspace: xp2 64 MiB | Wf 512 KiB | hf 64 KiB
  char* ws = (char*)d_ws;
  u16*  xp2 = (u16*)ws;
  u16*  Wf  = (u16*)(ws + (size_t)67108864);
  float* hf = (float*)(ws + (size_t)67108864 + 524288);

  k_prep <<<128, 256, 0, stream>>>(whh_f, Wf);
  k_xproj<<<dim3(16, 512), 256, 0, stream>>>(x, emb, wih_f, bih_f, bhh_f, xp2);
  k_rnn  <<<4, 512, 147968, stream>>>(Wf, xp2, hf);
  k_tail <<<BATCH, 256, 0, stream>>>(x, emb, wih_b, bih_b, bhh_b,
                                     fc1w, fc1b, fc2w, fc2b, hf, out);
}